// Round 6
// baseline (1095.773 us; speedup 1.0000x reference)
//
#include <hip/hip_runtime.h>
#include <stdint.h>

#define IN_F 4096
#define OUT_F 4096
#define NROWS 8192

typedef __attribute__((ext_vector_type(4))) int int4v;
typedef __attribute__((ext_vector_type(8))) int int8v;
typedef __attribute__((ext_vector_type(16))) float f32x16;

// ---- kernel 1: fp8-quantize x AND partial spline dot-products s = x . CP^T ----
__global__ __launch_bounds__(256) void xq_s(const float* __restrict__ x,
                                            const float* __restrict__ cp,
                                            unsigned char* __restrict__ xb,
                                            float* __restrict__ ps) {
  __shared__ float4 cps[9 * 128];
  const int b = blockIdx.x;
  const int rg = b >> 3, ck = b & 7;
  const int tid = threadIdx.x;
  for (int i = tid; i < 9 * 128; i += 256) {
    const int j = i >> 7, c = i & 127;
    cps[i] = ((const float4*)(cp + (size_t)j * IN_F + ck * 512))[c];
  }
  __syncthreads();
  const int row = rg * 32 + (tid >> 3);
  const int c0 = ck * 512 + (tid & 7) * 64;
  const float4* xr = (const float4*)(x + (size_t)row * IN_F + c0);
  uint32_t* xo = (uint32_t*)(xb + (size_t)row * IN_F + c0);
  float p[9] = {0, 0, 0, 0, 0, 0, 0, 0, 0};
  #pragma unroll 4
  for (int g = 0; g < 16; ++g) {
    float4 v = xr[g];
    const int cc = (tid & 7) * 16 + g;
    #pragma unroll
    for (int j = 0; j < 9; ++j) {
      float4 w = cps[j * 128 + cc];
      p[j] += v.x * w.x + v.y * w.y + v.z * w.z + v.w * w.w;
    }
    int pk = __builtin_amdgcn_cvt_pk_fp8_f32(v.x, v.y, 0, false);
    pk = __builtin_amdgcn_cvt_pk_fp8_f32(v.z, v.w, pk, true);
    xo[g] = (uint32_t)pk;
  }
  #pragma unroll
  for (int j = 0; j < 9; ++j) {
    float v = p[j];
    v += __shfl_xor(v, 1);
    v += __shfl_xor(v, 2);
    v += __shfl_xor(v, 4);
    p[j] = v;
  }
  if ((tid & 7) == 0) {
    float* outp = ps + ((size_t)row * 8 + ck) * 9;
    #pragma unroll
    for (int j = 0; j < 9; ++j) outp[j] = p[j];
  }
}

// ---- kernel 2: reduce 8 chunk-partials -> s[8192][9] ----
__global__ void s_reduce(const float* __restrict__ ps, float* __restrict__ s) {
  const int row = blockIdx.x * 256 + threadIdx.x;
  const float* pr = ps + (size_t)row * 72;
  #pragma unroll
  for (int j = 0; j < 9; ++j) {
    float v = 0.f;
    #pragma unroll
    for (int k = 0; k < 8; ++k) v += pr[k * 9 + j];
    s[row * 9 + j] = v;
  }
}

// ---- kernel 3: resid * 64 -> fp8 e4m3 ----
__global__ __launch_bounds__(256) void rq(const float* __restrict__ r,
                                          unsigned char* __restrict__ rb) {
  const int i = blockIdx.x * 256 + threadIdx.x;
  const float4* rv = (const float4*)r + (size_t)i * 4;
  uint32_t pk4[4];
  #pragma unroll
  for (int g = 0; g < 4; ++g) {
    float4 v = rv[g];
    int pk = __builtin_amdgcn_cvt_pk_fp8_f32(v.x * 64.f, v.y * 64.f, 0, false);
    pk = __builtin_amdgcn_cvt_pk_fp8_f32(v.z * 64.f, v.w * 64.f, pk, true);
    pk4[g] = (uint32_t)pk;
  }
  ((uint4*)rb)[i] = make_uint4(pk4[0], pk4[1], pk4[2], pk4[3]);
}

#define MFMA_FP8(d, av, bv) \
  d = __builtin_amdgcn_mfma_scale_f32_32x32x64_f8f6f4( \
      av, bv, d, 0, 0, 0, 0x7F7F7F7F, 0, 0x7F7F7F7F)

// ---- kernel 4: y = (xb . rb^T)/64 + spline(s) + bias ----
// 128x128 tile, BK=128 (fp8 row = 128B = verified zero-conflict geometry),
// 4 waves (2x2, 64x64 each), single-buffer 32KB LDS + 2-barrier skeleton
// (round-1-proven), 4 blocks/CU. 16B-slot XOR swizzle slot^=(r&7) both-sides:
// inverse-swizzled global source for linear global_load_lds dest + swizzled
// ds_read. 8 MFMAs (32x32x64) per barrier interval.
__global__ __launch_bounds__(256, 4) void gemm_fp8(
    const unsigned char* __restrict__ A,   // xb [8192][4096]
    const unsigned char* __restrict__ B,   // rb [4096][4096] (x64)
    const float* __restrict__ S,           // s [8192][9]
    const float* __restrict__ bias,
    float* __restrict__ C) {
  __shared__ unsigned char lds[2][128 * 128];   // [A|B], 16 KiB each

  const int tid = threadIdx.x;
  const int lane = tid & 63;
  const int wave = tid >> 6;    // 0..3
  const int wr = wave >> 1;     // M half of tile
  const int wn = wave & 1;      // N half
  const int l31 = lane & 31;
  const int lh = lane >> 5;

  // XCD-aware swizzle (2048 % 8 == 0 -> bijective)
  const int bs = (blockIdx.x & 7) * 256 + (blockIdx.x >> 3);
  const int bm = bs >> 5;       // 64 M-tiles
  const int bn = bs & 31;       // 32 N-tiles
  const size_t row0 = (size_t)bm * 128;
  const size_t col0 = (size_t)bn * 128;

  // stage 128 rows x 128B of A(ab=0)/B(ab=1), K-tile kt (4 issues of 32 rows)
  auto stage = [&](int ab, const unsigned char* __restrict__ src, size_t grow0,
                   int kt) {
    #pragma unroll
    for (int q = 0; q < 4; ++q) {
      const int r = q * 32 + (tid >> 3);                  // tile-local row
      const int sl = (tid & 7) ^ (r & 7);                 // inverse-swizzled slot
      const unsigned char* g =
          src + (grow0 + r) * (size_t)IN_F + kt * 128 + sl * 16;
      unsigned char* d = &lds[ab][q * 4096] + wave * 1024;  // wave-uniform base
      __builtin_amdgcn_global_load_lds(
          (const __attribute__((address_space(1))) void*)g,
          (__attribute__((address_space(3))) void*)d, 16, 0, 0);
    }
  };
  // one 16B piece of a 32-row operand: rows rbase+l31, k-slot (kk*4+lh*2)^swz, ^j
  auto ldf = [&](int ab, int rbase, int kk, int j) -> int4v {
    const int r = rbase + l31;
    const int sl = ((kk * 4 + lh * 2) ^ (r & 7)) ^ j;
    return *(const int4v*)&lds[ab][r * 128 + sl * 16];
  };

  f32x16 acc[2][2] = {};

  for (int kt = 0; kt < IN_F / 128; ++kt) {
    stage(0, A, row0, kt);
    stage(1, B, col0, kt);
    __syncthreads();   // vmcnt(0)+lgkm drain + barrier: tile visible
    #pragma unroll
    for (int kk = 0; kk < 2; ++kk) {
      union { int8v v8; int4v v4[2]; } a0, a1, b0, b1;
      a0.v4[0] = ldf(0, wr * 64 + 0,  kk, 0); a0.v4[1] = ldf(0, wr * 64 + 0,  kk, 1);
      a1.v4[0] = ldf(0, wr * 64 + 32, kk, 0); a1.v4[1] = ldf(0, wr * 64 + 32, kk, 1);
      b0.v4[0] = ldf(1, wn * 64 + 0,  kk, 0); b0.v4[1] = ldf(1, wn * 64 + 0,  kk, 1);
      b1.v4[0] = ldf(1, wn * 64 + 32, kk, 0); b1.v4[1] = ldf(1, wn * 64 + 32, kk, 1);
      __builtin_amdgcn_s_setprio(1);
      MFMA_FP8(acc[0][0], a0.v8, b0.v8);
      MFMA_FP8(acc[0][1], a0.v8, b1.v8);
      MFMA_FP8(acc[1][0], a1.v8, b0.v8);
      MFMA_FP8(acc[1][1], a1.v8, b1.v8);
      __builtin_amdgcn_s_setprio(0);
    }
    __syncthreads();   // all reads done before next stage overwrites
  }

  // epilogue: y = acc/64 + Catmull-Rom(o) . s[n][j-1..j+2] + bias[o]
  // D layout (32x32): col = lane&31, row = (reg&3) + 8*(reg>>2) + 4*(lane>>5)
  const float inv64 = 0.015625f;
  #pragma unroll
  for (int ni = 0; ni < 2; ++ni) {
    const int o = (int)col0 + wn * 64 + ni * 32 + l31;
    float ts = ((float)o / 4095.0f) * 8.0f;
    int j = (int)floorf(ts);
    j = j < 1 ? 1 : (j > 6 ? 6 : j);
    float t = ts - (float)j;
    float t2 = t * t, t3 = t2 * t;
    const float c0 = -0.5f * t3 + t2 - 0.5f * t;
    const float c1 = 1.5f * t3 - 2.5f * t2 + 1.0f;
    const float c2 = -1.5f * t3 + 2.0f * t2 + 0.5f * t;
    const float c3 = 0.5f * t3 - 0.5f * t2;
    const float bv = bias[o];
    #pragma unroll
    for (int mi = 0; mi < 2; ++mi) {
      #pragma unroll
      for (int rg = 0; rg < 16; ++rg) {
        const int n = (int)row0 + wr * 64 + mi * 32 + (rg & 3) + 8 * (rg >> 2) + 4 * lh;
        const float* sr = S + n * 9 + (j - 1);
        C[(size_t)n * OUT_F + o] =
            acc[mi][ni][rg] * inv64 + c0 * sr[0] + c1 * sr[1] + c2 * sr[2] + c3 * sr[3] + bv;
      }
    }
  }
}

// ---- safety net: fp32 tiled GEMM w/ on-the-fly weight ----
static __device__ __forceinline__ void cr_coeffs(int o, int& j, float& c0, float& c1,
                                                 float& c2, float& c3) {
  float ts = ((float)o / 4095.0f) * 8.0f;
  j = (int)floorf(ts);
  j = j < 1 ? 1 : (j > 6 ? 6 : j);
  float t = ts - (float)j;
  float t2 = t * t, t3 = t2 * t;
  c0 = -0.5f * t3 + t2 - 0.5f * t;
  c1 = 1.5f * t3 - 2.5f * t2 + 1.0f;
  c2 = -1.5f * t3 + 2.0f * t2 + 0.5f * t;
  c3 = 0.5f * t3 - 0.5f * t2;
}

__global__ void fallback_gemm(const float* __restrict__ x, const float* __restrict__ cp,
                              const float* __restrict__ resid, const float* __restrict__ bias,
                              float* __restrict__ out) {
  __shared__ float xs[64][32];
  __shared__ float ws[64][33];
  const int tid = threadIdx.x;
  const int bm = blockIdx.x / (OUT_F / 64);
  const int bn = blockIdx.x % (OUT_F / 64);
  const int row0 = bm * 64, col0 = bn * 64;
  const int tr = tid >> 4, tc = tid & 15;
  float acc[4][4] = {};
  for (int k0 = 0; k0 < IN_F; k0 += 32) {
    #pragma unroll
    for (int q = 0; q < 8; ++q) {
      int e = q * 256 + tid;
      int r = e >> 5, cc = e & 31;
      xs[r][cc] = x[(size_t)(row0 + r) * IN_F + k0 + cc];
      int o = col0 + r;
      int j; float c0, c1, c2, c3;
      cr_coeffs(o, j, c0, c1, c2, c3);
      size_t ci = (size_t)(j - 1) * IN_F + k0 + cc;
      ws[r][cc] = c0 * cp[ci] + c1 * cp[ci + IN_F] + c2 * cp[ci + 2 * IN_F] +
                  c3 * cp[ci + 3 * IN_F] + resid[(size_t)o * IN_F + k0 + cc];
    }
    __syncthreads();
    #pragma unroll
    for (int kk = 0; kk < 32; ++kk) {
      float xv[4], wv[4];
      #pragma unroll
      for (int i = 0; i < 4; ++i) xv[i] = xs[tr * 4 + i][kk];
      #pragma unroll
      for (int i = 0; i < 4; ++i) wv[i] = ws[tc * 4 + i][kk];
      #pragma unroll
      for (int i = 0; i < 4; ++i)
        #pragma unroll
        for (int jj = 0; jj < 4; ++jj) acc[i][jj] += xv[i] * wv[jj];
    }
    __syncthreads();
  }
  #pragma unroll
  for (int i = 0; i < 4; ++i)
    #pragma unroll
    for (int jj = 0; jj < 4; ++jj) {
      int row = row0 + tr * 4 + i, col = col0 + tc * 4 + jj;
      out[(size_t)row * OUT_F + col] = acc[i][jj] + bias[col];
    }
}

extern "C" void kernel_launch(void* const* d_in, const int* in_sizes, int n_in,
                              void* d_out, int out_size, void* d_ws, size_t ws_size,
                              hipStream_t stream) {
  const float* x = (const float*)d_in[0];
  const float* cp = (const float*)d_in[1];
  const float* resid = (const float*)d_in[2];
  const float* bias = (const float*)d_in[3];
  float* out = (float*)d_out;

  const size_t xb_b = (size_t)NROWS * IN_F;        // 33,554,432
  const size_t rb_b = (size_t)OUT_F * IN_F;        // 16,777,216
  const size_t s_b = (size_t)NROWS * 9 * 4;        // 294,912
  const size_t ps_b = (size_t)NROWS * 72 * 4;      // 2,359,296

  if (ws_size >= xb_b + rb_b + s_b + ps_b) {
    unsigned char* xb = (unsigned char*)d_ws;
    unsigned char* rb = xb + xb_b;
    float* s = (float*)(rb + rb_b);
    float* ps = (float*)((unsigned char*)s + s_b);
    hipLaunchKernelGGL(xq_s, dim3(2048), dim3(256), 0, stream, x, cp, xb, ps);
    hipLaunchKernelGGL(s_reduce, dim3(32), dim3(256), 0, stream, ps, s);
    hipLaunchKernelGGL(rq, dim3(4096), dim3(256), 0, stream, resid, rb);
    hipLaunchKernelGGL(gemm_fp8, dim3(2048), dim3(256), 0, stream, xb, rb, s, bias, out);
  } else {
    hipLaunchKernelGGL(fallback_gemm, dim3((NROWS / 64) * (OUT_F / 64)), dim3(256), 0,
                       stream, x, cp, resid, bias, out);
  }
}

// Round 7
// 406.370 us; speedup vs baseline: 2.6965x; 2.6965x over previous
//
#include <hip/hip_runtime.h>
#include <stdint.h>

#define IN_F 4096
#define OUT_F 4096
#define NROWS 8192

typedef __attribute__((ext_vector_type(4))) int int4v;
typedef __attribute__((ext_vector_type(8))) int int8v;
typedef __attribute__((ext_vector_type(4))) float floatx4;

// ---- kernel 1: fp8-quantize x AND partial spline dot-products s = x . CP^T ----
__global__ __launch_bounds__(256) void xq_s(const float* __restrict__ x,
                                            const float* __restrict__ cp,
                                            unsigned char* __restrict__ xb,
                                            float* __restrict__ ps) {
  __shared__ float4 cps[9 * 128];
  const int b = blockIdx.x;
  const int rg = b >> 3, ck = b & 7;
  const int tid = threadIdx.x;
  for (int i = tid; i < 9 * 128; i += 256) {
    const int j = i >> 7, c = i & 127;
    cps[i] = ((const float4*)(cp + (size_t)j * IN_F + ck * 512))[c];
  }
  __syncthreads();
  const int row = rg * 32 + (tid >> 3);
  const int c0 = ck * 512 + (tid & 7) * 64;
  const float4* xr = (const float4*)(x + (size_t)row * IN_F + c0);
  uint32_t* xo = (uint32_t*)(xb + (size_t)row * IN_F + c0);
  float p[9] = {0, 0, 0, 0, 0, 0, 0, 0, 0};
  #pragma unroll 4
  for (int g = 0; g < 16; ++g) {
    float4 v = xr[g];
    const int cc = (tid & 7) * 16 + g;
    #pragma unroll
    for (int j = 0; j < 9; ++j) {
      float4 w = cps[j * 128 + cc];
      p[j] += v.x * w.x + v.y * w.y + v.z * w.z + v.w * w.w;
    }
    int pk = __builtin_amdgcn_cvt_pk_fp8_f32(v.x, v.y, 0, false);
    pk = __builtin_amdgcn_cvt_pk_fp8_f32(v.z, v.w, pk, true);
    xo[g] = (uint32_t)pk;
  }
  #pragma unroll
  for (int j = 0; j < 9; ++j) {
    float v = p[j];
    v += __shfl_xor(v, 1);
    v += __shfl_xor(v, 2);
    v += __shfl_xor(v, 4);
    p[j] = v;
  }
  if ((tid & 7) == 0) {
    float* outp = ps + ((size_t)row * 8 + ck) * 9;
    #pragma unroll
    for (int j = 0; j < 9; ++j) outp[j] = p[j];
  }
}

// ---- kernel 2: reduce 8 chunk-partials -> s[8192][9] ----
__global__ void s_reduce(const float* __restrict__ ps, float* __restrict__ s) {
  const int row = blockIdx.x * 256 + threadIdx.x;
  const float* pr = ps + (size_t)row * 72;
  #pragma unroll
  for (int j = 0; j < 9; ++j) {
    float v = 0.f;
    #pragma unroll
    for (int k = 0; k < 8; ++k) v += pr[k * 9 + j];
    s[row * 9 + j] = v;
  }
}

// ---- kernel 3: resid * 64 -> fp8 e4m3 ----
__global__ __launch_bounds__(256) void rq(const float* __restrict__ r,
                                          unsigned char* __restrict__ rb) {
  const int i = blockIdx.x * 256 + threadIdx.x;
  const float4* rv = (const float4*)r + (size_t)i * 4;
  uint32_t pk4[4];
  #pragma unroll
  for (int g = 0; g < 4; ++g) {
    float4 v = rv[g];
    int pk = __builtin_amdgcn_cvt_pk_fp8_f32(v.x * 64.f, v.y * 64.f, 0, false);
    pk = __builtin_amdgcn_cvt_pk_fp8_f32(v.z * 64.f, v.w * 64.f, pk, true);
    pk4[g] = (uint32_t)pk;
  }
  ((uint4*)rb)[i] = make_uint4(pk4[0], pk4[1], pk4[2], pk4[3]);
}

#define MFMA_FP8_16(d, av, bv) \
  d = __builtin_amdgcn_mfma_scale_f32_16x16x128_f8f6f4( \
      av, bv, d, 0, 0, 0, 0x7F7F7F7F, 0, 0x7F7F7F7F)

// ---- kernel 4: y = (xb . rb^T)/64 + spline(s) + bias ----
// EXACT round-1 skeleton at fp8/K=128: 128x128 tile, 4 waves (2x2, 64x64),
// BK=128 -> LDS tile 128 rows x 128 B (byte-identical to round-1 bf16 tile,
// measured 0 bank conflicts), 32 KB LDS single-buffered -> 4 blocks/CU,
// stage -> sync -> 16 ds_read_b128 + 16 MFMA -> sync. 16B-slot XOR swizzle
// slot^=(r&7) both-sides (inverse-swizzled global source, linear LDS dest).
__global__ __launch_bounds__(256, 4) void gemm_fp8(
    const unsigned char* __restrict__ A,   // xb [8192][4096]
    const unsigned char* __restrict__ B,   // rb [4096][4096] (x64)
    const float* __restrict__ S,           // s [8192][9]
    const float* __restrict__ bias,
    float* __restrict__ C) {
  __shared__ unsigned char As[128 * 128];
  __shared__ unsigned char Bs[128 * 128];

  const int tid = threadIdx.x;
  const int lane = tid & 63;
  const int wave = tid >> 6;    // 0..3
  const int wr = wave >> 1;     // M half (64 rows)
  const int wn = wave & 1;      // N half (64 cols)
  const int l15 = lane & 15;
  const int l4 = lane >> 4;     // 0..3  (32B k-chunk)

  // XCD-aware swizzle (2048 % 8 == 0 -> bijective)
  const int bs = (blockIdx.x & 7) * 256 + (blockIdx.x >> 3);
  const int bm = bs >> 5;       // 64 M-tiles
  const int bn = bs & 31;       // 32 N-tiles
  const size_t row0 = (size_t)bm * 128;
  const size_t col0 = (size_t)bn * 128;

  floatx4 acc[4][4] = {};

  for (int kt = 0; kt < IN_F / 128; ++kt) {
    const int k0 = kt * 128;
    // stage 128x128B tiles of A and B (16 wave-issues of 1 KB each, linear)
    #pragma unroll
    for (int q = 0; q < 4; ++q) {
      const int issue = q * 4 + wave;
      const int ofs16 = issue * 64 + lane;       // 16B-slot index in tile
      const int r = ofs16 >> 3;                  // row (8 slots of 16B per row)
      const int sl = (ofs16 & 7) ^ (r & 7);      // inverse-swizzled slot
      const unsigned char* ga = A + (row0 + r) * (size_t)IN_F + k0 + sl * 16;
      const unsigned char* gb = B + (col0 + r) * (size_t)IN_F + k0 + sl * 16;
      __builtin_amdgcn_global_load_lds(
          (const __attribute__((address_space(1))) void*)ga,
          (__attribute__((address_space(3))) void*)(As + issue * 1024), 16, 0, 0);
      __builtin_amdgcn_global_load_lds(
          (const __attribute__((address_space(1))) void*)gb,
          (__attribute__((address_space(3))) void*)(Bs + issue * 1024), 16, 0, 0);
    }
    __syncthreads();

    // B fragments: lane holds col wn*64+n*16+l15, k-bytes [l4*32, l4*32+32)
    union { int8v v8; int4v v4[2]; } bf[4];
    #pragma unroll
    for (int n = 0; n < 4; ++n) {
      const int r = wn * 64 + n * 16 + l15;
      const int s0 = (l4 * 2) ^ (r & 7);
      const int s1 = (l4 * 2 + 1) ^ (r & 7);
      bf[n].v4[0] = *(const int4v*)(Bs + r * 128 + s0 * 16);
      bf[n].v4[1] = *(const int4v*)(Bs + r * 128 + s1 * 16);
    }
    #pragma unroll
    for (int m = 0; m < 4; ++m) {
      union { int8v v8; int4v v4[2]; } af;
      const int r = wr * 64 + m * 16 + l15;
      const int s0 = (l4 * 2) ^ (r & 7);
      const int s1 = (l4 * 2 + 1) ^ (r & 7);
      af.v4[0] = *(const int4v*)(As + r * 128 + s0 * 16);
      af.v4[1] = *(const int4v*)(As + r * 128 + s1 * 16);
      #pragma unroll
      for (int n = 0; n < 4; ++n)
        MFMA_FP8_16(acc[m][n], af.v8, bf[n].v8);
    }
    __syncthreads();
  }

  // epilogue: y = acc/64 + Catmull-Rom(o) . s[row][j-1..j+2] + bias[o]
  // D layout (16x16): col = lane&15, row = (lane>>4)*4 + reg  [verified]
  const float inv64 = 0.015625f;
  #pragma unroll
  for (int n = 0; n < 4; ++n) {
    const int o = (int)col0 + wn * 64 + n * 16 + l15;
    float ts = ((float)o / 4095.0f) * 8.0f;
    int j = (int)floorf(ts);
    j = j < 1 ? 1 : (j > 6 ? 6 : j);
    float t = ts - (float)j;
    float t2 = t * t, t3 = t2 * t;
    const float c0 = -0.5f * t3 + t2 - 0.5f * t;
    const float c1 = 1.5f * t3 - 2.5f * t2 + 1.0f;
    const float c2 = -1.5f * t3 + 2.0f * t2 + 0.5f * t;
    const float c3 = 0.5f * t3 - 0.5f * t2;
    const float bv = bias[o];
    #pragma unroll
    for (int m = 0; m < 4; ++m) {
      const int rw = (int)row0 + wr * 64 + m * 16 + l4 * 4;
      #pragma unroll
      for (int r = 0; r < 4; ++r) {
        const int nrow = rw + r;
        const float* sr = S + nrow * 9 + (j - 1);
        C[(size_t)nrow * OUT_F + o] =
            acc[m][n][r] * inv64 + c0 * sr[0] + c1 * sr[1] + c2 * sr[2] + c3 * sr[3] + bv;
      }
    }
  }
}

// ---- safety net: fp32 tiled GEMM w/ on-the-fly weight ----
static __device__ __forceinline__ void cr_coeffs(int o, int& j, float& c0, float& c1,
                                                 float& c2, float& c3) {
  float ts = ((float)o / 4095.0f) * 8.0f;
  j = (int)floorf(ts);
  j = j < 1 ? 1 : (j > 6 ? 6 : j);
  float t = ts - (float)j;
  float t2 = t * t, t3 = t2 * t;
  c0 = -0.5f * t3 + t2 - 0.5f * t;
  c1 = 1.5f * t3 - 2.5f * t2 + 1.0f;
  c2 = -1.5f * t3 + 2.0f * t2 + 0.5f * t;
  c3 = 0.5f * t3 - 0.5f * t2;
}

__global__ void fallback_gemm(const float* __restrict__ x, const float* __restrict__ cp,
                              const float* __restrict__ resid, const float* __restrict__ bias,
                              float* __restrict__ out) {
  __shared__ float xs[64][32];
  __shared__ float ws[64][33];
  const int tid = threadIdx.x;
  const int bm = blockIdx.x / (OUT_F / 64);
  const int bn = blockIdx.x % (OUT_F / 64);
  const int row0 = bm * 64, col0 = bn * 64;
  const int tr = tid >> 4, tc = tid & 15;
  float acc[4][4] = {};
  for (int k0 = 0; k0 < IN_F; k0 += 32) {
    #pragma unroll
    for (int q = 0; q < 8; ++q) {
      int e = q * 256 + tid;
      int r = e >> 5, cc = e & 31;
      xs[r][cc] = x[(size_t)(row0 + r) * IN_F + k0 + cc];
      int o = col0 + r;
      int j; float c0, c1, c2, c3;
      cr_coeffs(o, j, c0, c1, c2, c3);
      size_t ci = (size_t)(j - 1) * IN_F + k0 + cc;
      ws[r][cc] = c0 * cp[ci] + c1 * cp[ci + IN_F] + c2 * cp[ci + 2 * IN_F] +
                  c3 * cp[ci + 3 * IN_F] + resid[(size_t)o * IN_F + k0 + cc];
    }
    __syncthreads();
    #pragma unroll
    for (int kk = 0; kk < 32; ++kk) {
      float xv[4], wv[4];
      #pragma unroll
      for (int i = 0; i < 4; ++i) xv[i] = xs[tr * 4 + i][kk];
      #pragma unroll
      for (int i = 0; i < 4; ++i) wv[i] = ws[tc * 4 + i][kk];
      #pragma unroll
      for (int i = 0; i < 4; ++i)
        #pragma unroll
        for (int jj = 0; jj < 4; ++jj) acc[i][jj] += xv[i] * wv[jj];
    }
    __syncthreads();
  }
  #pragma unroll
  for (int i = 0; i < 4; ++i)
    #pragma unroll
    for (int jj = 0; jj < 4; ++jj) {
      int row = row0 + tr * 4 + i, col = col0 + tc * 4 + jj;
      out[(size_t)row * OUT_F + col] = acc[i][jj] + bias[col];
    }
}

extern "C" void kernel_launch(void* const* d_in, const int* in_sizes, int n_in,
                              void* d_out, int out_size, void* d_ws, size_t ws_size,
                              hipStream_t stream) {
  const float* x = (const float*)d_in[0];
  const float* cp = (const float*)d_in[1];
  const float* resid = (const float*)d_in[2];
  const float* bias = (const float*)d_in[3];
  float* out = (float*)d_out;

  const size_t xb_b = (size_t)NROWS * IN_F;        // 33,554,432
  const size_t rb_b = (size_t)OUT_F * IN_F;        // 16,777,216
  const size_t s_b = (size_t)NROWS * 9 * 4;        // 294,912
  const size_t ps_b = (size_t)NROWS * 72 * 4;      // 2,359,296

  if (ws_size >= xb_b + rb_b + s_b + ps_b) {
    unsigned char* xb = (unsigned char*)d_ws;
    unsigned char* rb = xb + xb_b;
    float* s = (float*)(rb + rb_b);
    float* ps = (float*)((unsigned char*)s + s_b);
    hipLaunchKernelGGL(xq_s, dim3(2048), dim3(256), 0, stream, x, cp, xb, ps);
    hipLaunchKernelGGL(s_reduce, dim3(32), dim3(256), 0, stream, ps, s);
    hipLaunchKernelGGL(rq, dim3(4096), dim3(256), 0, stream, resid, rb);
    hipLaunchKernelGGL(gemm_fp8, dim3(2048), dim3(256), 0, stream, xb, rb, s, bias, out);
  } else {
    hipLaunchKernelGGL(fallback_gemm, dim3((NROWS / 64) * (OUT_F / 64)), dim3(256), 0,
                       stream, x, cp, resid, bias, out);
  }
}

// Round 8
// 298.053 us; speedup vs baseline: 3.6764x; 1.3634x over previous
//
#include <hip/hip_runtime.h>
#include <stdint.h>

#define IN_F 4096
#define OUT_F 4096
#define NROWS 8192
#define NT (IN_F / 64)   // 64 K-tiles of BK=64

typedef __attribute__((ext_vector_type(4))) int int4v;
typedef __attribute__((ext_vector_type(8))) int int8v;
typedef __attribute__((ext_vector_type(16))) float f32x16;

// ---- kernel 1: fp8-quantize x AND partial spline dot-products s = x . CP^T ----
__global__ __launch_bounds__(256) void xq_s(const float* __restrict__ x,
                                            const float* __restrict__ cp,
                                            unsigned char* __restrict__ xb,
                                            float* __restrict__ ps) {
  __shared__ float4 cps[9 * 128];
  const int b = blockIdx.x;
  const int rg = b >> 3, ck = b & 7;
  const int tid = threadIdx.x;
  for (int i = tid; i < 9 * 128; i += 256) {
    const int j = i >> 7, c = i & 127;
    cps[i] = ((const float4*)(cp + (size_t)j * IN_F + ck * 512))[c];
  }
  __syncthreads();
  const int row = rg * 32 + (tid >> 3);
  const int c0 = ck * 512 + (tid & 7) * 64;
  const float4* xr = (const float4*)(x + (size_t)row * IN_F + c0);
  uint32_t* xo = (uint32_t*)(xb + (size_t)row * IN_F + c0);
  float p[9] = {0, 0, 0, 0, 0, 0, 0, 0, 0};
  #pragma unroll 4
  for (int g = 0; g < 16; ++g) {
    float4 v = xr[g];
    const int cc = (tid & 7) * 16 + g;
    #pragma unroll
    for (int j = 0; j < 9; ++j) {
      float4 w = cps[j * 128 + cc];
      p[j] += v.x * w.x + v.y * w.y + v.z * w.z + v.w * w.w;
    }
    int pk = __builtin_amdgcn_cvt_pk_fp8_f32(v.x, v.y, 0, false);
    pk = __builtin_amdgcn_cvt_pk_fp8_f32(v.z, v.w, pk, true);
    xo[g] = (uint32_t)pk;
  }
  #pragma unroll
  for (int j = 0; j < 9; ++j) {
    float v = p[j];
    v += __shfl_xor(v, 1);
    v += __shfl_xor(v, 2);
    v += __shfl_xor(v, 4);
    p[j] = v;
  }
  if ((tid & 7) == 0) {
    float* outp = ps + ((size_t)row * 8 + ck) * 9;
    #pragma unroll
    for (int j = 0; j < 9; ++j) outp[j] = p[j];
  }
}

// ---- kernel 2: reduce 8 chunk-partials -> s[8192][9] ----
__global__ void s_reduce(const float* __restrict__ ps, float* __restrict__ s) {
  const int row = blockIdx.x * 256 + threadIdx.x;
  const float* pr = ps + (size_t)row * 72;
  #pragma unroll
  for (int j = 0; j < 9; ++j) {
    float v = 0.f;
    #pragma unroll
    for (int k = 0; k < 8; ++k) v += pr[k * 9 + j];
    s[row * 9 + j] = v;
  }
}

// ---- kernel 3: resid * 64 -> fp8 e4m3 ----
__global__ __launch_bounds__(256) void rq(const float* __restrict__ r,
                                          unsigned char* __restrict__ rb) {
  const int i = blockIdx.x * 256 + threadIdx.x;
  const float4* rv = (const float4*)r + (size_t)i * 4;
  uint32_t pk4[4];
  #pragma unroll
  for (int g = 0; g < 4; ++g) {
    float4 v = rv[g];
    int pk = __builtin_amdgcn_cvt_pk_fp8_f32(v.x * 64.f, v.y * 64.f, 0, false);
    pk = __builtin_amdgcn_cvt_pk_fp8_f32(v.z * 64.f, v.w * 64.f, pk, true);
    pk4[g] = (uint32_t)pk;
  }
  ((uint4*)rb)[i] = make_uint4(pk4[0], pk4[1], pk4[2], pk4[3]);
}

#define MFMA_FP8(d, av, bv) \
  d = __builtin_amdgcn_mfma_scale_f32_32x32x64_f8f6f4( \
      av, bv, d, 0, 0, 0, 0x7F7F7F7F, 0, 0x7F7F7F7F)

// ---- kernel 4: y = (xb . rb^T)/64 + spline(s) + bias ----
// Round-5-verified layouts + TRIPLE-buffered LDS for distance-2 prefetch:
// 128x128 tile, BK=64, 4 waves (2x2, 64x64), 48 KB LDS (3 bufs) -> 3 blk/CU.
// Interval t: issue stage(t+2) -> 8 ds_read + 4 MFMA of tile t ->
// lgkmcnt(0); vmcnt(4) (waits ONLY tile t+1, issued a full interval ago,
// never drains to 0 mid-loop) -> s_barrier. Single barrier per interval.
__global__ __launch_bounds__(256, 3) void gemm_fp8(
    const unsigned char* __restrict__ A,   // xb [8192][4096]
    const unsigned char* __restrict__ B,   // rb [4096][4096] (x64)
    const float* __restrict__ S,           // s [8192][9]
    const float* __restrict__ bias,
    float* __restrict__ C) {
  __shared__ unsigned char lds[3 * 16384];   // [buf][A|B][64 lines x 128 B]

  const int tid = threadIdx.x;
  const int lane = tid & 63;
  const int wave = tid >> 6;    // 0..3
  const int wr = wave >> 1;     // M half of tile
  const int wn = wave & 1;      // N half
  const int l31 = lane & 31;
  const int lh = lane >> 5;

  // XCD-aware swizzle (2048 % 8 == 0 -> bijective)
  const int bs = (blockIdx.x & 7) * 256 + (blockIdx.x >> 3);
  const int bm = bs >> 5;       // 64 M-tiles
  const int bn = bs & 31;       // 32 N-tiles
  const size_t row0 = (size_t)bm * 128;
  const size_t col0 = (size_t)bn * 128;

  // stage 64 fp8-rows [half*64, half*64+64) of A(ab=0)/B(ab=1), tile kt -> buf
  // (r5-verified: linear LDS dest, inverse-swizzled global source; rows packed
  //  2-per-128B-line, 16B-slot swizzle sl^=(L&7))
  auto stage = [&](int buf, int ab, int half, const unsigned char* __restrict__ src,
                   size_t grow0, int kt) {
    const int ls = (tid & 7) ^ ((tid >> 3) & 7);
    const int r = half * 64 + 2 * (tid >> 3) + (ls >> 2);
    const unsigned char* g = src + (grow0 + r) * (size_t)IN_F + kt * 64 + (ls & 3) * 16;
    unsigned char* d = lds + buf * 16384 + ab * 8192 + half * 4096 + (tid >> 6) * 1024;
    __builtin_amdgcn_global_load_lds(
        (const __attribute__((address_space(1))) void*)g,
        (__attribute__((address_space(3))) void*)d, 16, 0, 0);
  };
  auto stage_tile = [&](int buf, int kt) {
    stage(buf, 0, 0, A, row0, kt); stage(buf, 0, 1, A, row0, kt);
    stage(buf, 1, 0, B, col0, kt); stage(buf, 1, 1, B, col0, kt);
  };
  // one b128 of a 32-row operand (r5-verified)
  auto ldf = [&](int buf, int ab, int rbase, int s2) -> int4v {
    const int r = rbase + l31;
    const int sl = (r & 1) * 4 + lh * 2 + s2;
    const int L = r >> 1;
    return *(const int4v*)&lds[buf * 16384 + ab * 8192 + L * 128 + ((sl ^ (L & 7)) * 16)];
  };

  f32x16 acc[2][2] = {};

  // prologue: stage tiles 0 and 1; wait tile 0 (8 in flight -> vmcnt(4))
  stage_tile(0, 0);
  stage_tile(1, 1);
  asm volatile("s_waitcnt vmcnt(4)" ::: "memory");
  __builtin_amdgcn_s_barrier();

  int cur = 0, nx2 = 2;   // t%3, (t+2)%3 rotating
  #pragma unroll 1
  for (int t = 0; t < NT; ++t) {
    const bool more = (t + 2 < NT);
    if (more) stage_tile(nx2, t + 2);

    union { int8v v8; int4v v4[2]; } a0, a1, b0, b1;
    a0.v4[0] = ldf(cur, 0, wr * 64 + 0,  0); a0.v4[1] = ldf(cur, 0, wr * 64 + 0,  1);
    a1.v4[0] = ldf(cur, 0, wr * 64 + 32, 0); a1.v4[1] = ldf(cur, 0, wr * 64 + 32, 1);
    b0.v4[0] = ldf(cur, 1, wn * 64 + 0,  0); b0.v4[1] = ldf(cur, 1, wn * 64 + 0,  1);
    b1.v4[0] = ldf(cur, 1, wn * 64 + 32, 0); b1.v4[1] = ldf(cur, 1, wn * 64 + 32, 1);
    __builtin_amdgcn_s_setprio(1);
    MFMA_FP8(acc[0][0], a0.v8, b0.v8);
    MFMA_FP8(acc[0][1], a0.v8, b1.v8);
    MFMA_FP8(acc[1][0], a1.v8, b0.v8);
    MFMA_FP8(acc[1][1], a1.v8, b1.v8);
    __builtin_amdgcn_s_setprio(0);

    // my ds_reads drained (MFMAs consumed them; make it explicit), then wait
    // tile t+1 landed (oldest 4 of <=8 outstanding), then barrier.
    asm volatile("s_waitcnt lgkmcnt(0)" ::: "memory");
    if (more) {
      asm volatile("s_waitcnt vmcnt(4)" ::: "memory");
    } else {
      asm volatile("s_waitcnt vmcnt(0)" ::: "memory");
    }
    __builtin_amdgcn_s_barrier();

    cur = (cur == 2) ? 0 : cur + 1;
    nx2 = (nx2 == 2) ? 0 : nx2 + 1;
  }

  // epilogue: y = acc/64 + Catmull-Rom(o) . s[n][j-1..j+2] + bias[o]
  // D layout (32x32): col = lane&31, row = (reg&3) + 8*(reg>>2) + 4*(lane>>5)
  const float inv64 = 0.015625f;
  #pragma unroll
  for (int ni = 0; ni < 2; ++ni) {
    const int o = (int)col0 + wn * 64 + ni * 32 + l31;
    float ts = ((float)o / 4095.0f) * 8.0f;
    int j = (int)floorf(ts);
    j = j < 1 ? 1 : (j > 6 ? 6 : j);
    float t = ts - (float)j;
    float t2 = t * t, t3 = t2 * t;
    const float c0 = -0.5f * t3 + t2 - 0.5f * t;
    const float c1 = 1.5f * t3 - 2.5f * t2 + 1.0f;
    const float c2 = -1.5f * t3 + 2.0f * t2 + 0.5f * t;
    const float c3 = 0.5f * t3 - 0.5f * t2;
    const float bv = bias[o];
    #pragma unroll
    for (int mi = 0; mi < 2; ++mi) {
      #pragma unroll
      for (int rg = 0; rg < 16; ++rg) {
        const int n = (int)row0 + wr * 64 + mi * 32 + (rg & 3) + 8 * (rg >> 2) + 4 * lh;
        const float* sr = S + n * 9 + (j - 1);
        C[(size_t)n * OUT_F + o] =
            acc[mi][ni][rg] * inv64 + c0 * sr[0] + c1 * sr[1] + c2 * sr[2] + c3 * sr[3] + bv;
      }
    }
  }
}

// ---- safety net: fp32 tiled GEMM w/ on-the-fly weight ----
static __device__ __forceinline__ void cr_coeffs(int o, int& j, float& c0, float& c1,
                                                 float& c2, float& c3) {
  float ts = ((float)o / 4095.0f) * 8.0f;
  j = (int)floorf(ts);
  j = j < 1 ? 1 : (j > 6 ? 6 : j);
  float t = ts - (float)j;
  float t2 = t * t, t3 = t2 * t;
  c0 = -0.5f * t3 + t2 - 0.5f * t;
  c1 = 1.5f * t3 - 2.5f * t2 + 1.0f;
  c2 = -1.5f * t3 + 2.0f * t2 + 0.5f * t;
  c3 = 0.5f * t3 - 0.5f * t2;
}

__global__ void fallback_gemm(const float* __restrict__ x, const float* __restrict__ cp,
                              const float* __restrict__ resid, const float* __restrict__ bias,
                              float* __restrict__ out) {
  __shared__ float xs[64][32];
  __shared__ float ws[64][33];
  const int tid = threadIdx.x;
  const int bm = blockIdx.x / (OUT_F / 64);
  const int bn = blockIdx.x % (OUT_F / 64);
  const int row0 = bm * 64, col0 = bn * 64;
  const int tr = tid >> 4, tc = tid & 15;
  float acc[4][4] = {};
  for (int k0 = 0; k0 < IN_F; k0 += 32) {
    #pragma unroll
    for (int q = 0; q < 8; ++q) {
      int e = q * 256 + tid;
      int r = e >> 5, cc = e & 31;
      xs[r][cc] = x[(size_t)(row0 + r) * IN_F + k0 + cc];
      int o = col0 + r;
      int j; float c0, c1, c2, c3;
      cr_coeffs(o, j, c0, c1, c2, c3);
      size_t ci = (size_t)(j - 1) * IN_F + k0 + cc;
      ws[r][cc] = c0 * cp[ci] + c1 * cp[ci + IN_F] + c2 * cp[ci + 2 * IN_F] +
                  c3 * cp[ci + 3 * IN_F] + resid[(size_t)o * IN_F + k0 + cc];
    }
    __syncthreads();
    #pragma unroll
    for (int kk = 0; kk < 32; ++kk) {
      float xv[4], wv[4];
      #pragma unroll
      for (int i = 0; i < 4; ++i) xv[i] = xs[tr * 4 + i][kk];
      #pragma unroll
      for (int i = 0; i < 4; ++i) wv[i] = ws[tc * 4 + i][kk];
      #pragma unroll
      for (int i = 0; i < 4; ++i)
        #pragma unroll
        for (int jj = 0; jj < 4; ++jj) acc[i][jj] += xv[i] * wv[jj];
    }
    __syncthreads();
  }
  #pragma unroll
  for (int i = 0; i < 4; ++i)
    #pragma unroll
    for (int jj = 0; jj < 4; ++jj) {
      int row = row0 + tr * 4 + i, col = col0 + tc * 4 + jj;
      out[(size_t)row * OUT_F + col] = acc[i][jj] + bias[col];
    }
}

extern "C" void kernel_launch(void* const* d_in, const int* in_sizes, int n_in,
                              void* d_out, int out_size, void* d_ws, size_t ws_size,
                              hipStream_t stream) {
  const float* x = (const float*)d_in[0];
  const float* cp = (const float*)d_in[1];
  const float* resid = (const float*)d_in[2];
  const float* bias = (const float*)d_in[3];
  float* out = (float*)d_out;

  const size_t xb_b = (size_t)NROWS * IN_F;        // 33,554,432
  const size_t rb_b = (size_t)OUT_F * IN_F;        // 16,777,216
  const size_t s_b = (size_t)NROWS * 9 * 4;        // 294,912
  const size_t ps_b = (size_t)NROWS * 72 * 4;      // 2,359,296

  if (ws_size >= xb_b + rb_b + s_b + ps_b) {
    unsigned char* xb = (unsigned char*)d_ws;
    unsigned char* rb = xb + xb_b;
    float* s = (float*)(rb + rb_b);
    float* ps = (float*)((unsigned char*)s + s_b);
    hipLaunchKernelGGL(xq_s, dim3(2048), dim3(256), 0, stream, x, cp, xb, ps);
    hipLaunchKernelGGL(s_reduce, dim3(32), dim3(256), 0, stream, ps, s);
    hipLaunchKernelGGL(rq, dim3(4096), dim3(256), 0, stream, resid, rb);
    hipLaunchKernelGGL(gemm_fp8, dim3(2048), dim3(256), 0, stream, xb, rb, s, bias, out);
  } else {
    hipLaunchKernelGGL(fallback_gemm, dim3((NROWS / 64) * (OUT_F / 64)), dim3(256), 0,
                       stream, x, cp, resid, bias, out);
  }
}

// Round 10
// 257.513 us; speedup vs baseline: 4.2552x; 1.1574x over previous
//
#include <hip/hip_runtime.h>
#include <stdint.h>

#define IN_F 4096
#define OUT_F 4096
#define NROWS 8192
#define NT (IN_F / 64)   // 64 K-tiles of BK=64

typedef __attribute__((ext_vector_type(4))) int int4v;
typedef __attribute__((ext_vector_type(8))) int int8v;
typedef __attribute__((ext_vector_type(16))) float f32x16;
typedef __attribute__((ext_vector_type(4))) float floatx4;
typedef __attribute__((ext_vector_type(8))) short short8;

static __device__ __forceinline__ unsigned short f2bf(float f) {
  union { float f; unsigned int u; } v; v.f = f;
  unsigned int u = v.u;
  return (unsigned short)((u + 0x7FFFu + ((u >> 16) & 1u)) >> 16);
}

// ---- prepass 1 (fused): xb = fp8(x)  AND  ps[h] = partial s = x . CP^T ----
// grid 1024 = 512 row-groups(16 rows) x 2 K-halves; 256 thr; wave w owns
// K-quarter of the half (512 cols = 16 MFMA steps of 16x16x32 bf16).
// Frag maps (r1-verified): A/B row = lane&15, k-chunk = lane>>4 (consistent
// A/B map -> permutation cancels); C/D: col = lane&15, row = (lane>>4)*4+reg.
__global__ __launch_bounds__(256) void xqs_mfma(const float* __restrict__ x,
                                                const float* __restrict__ cp,
                                                unsigned char* __restrict__ xb,
                                                float* __restrict__ ps) {
  __shared__ float red[4][16][16];
  const int b = blockIdx.x;
  const int rg = b >> 1, h = b & 1;
  const int tid = threadIdx.x;
  const int lane = tid & 63, wave = tid >> 6;
  const int l15 = lane & 15, l4 = lane >> 4;
  const int row = rg * 16 + l15;
  const int kbase = h * 2048 + wave * 512;

  floatx4 acc = {};
  #pragma unroll 4
  for (int it = 0; it < 16; ++it) {
    const int k0 = kbase + it * 32 + l4 * 8;
    const float4 xa = *(const float4*)(x + (size_t)row * IN_F + k0);
    const float4 xc = *(const float4*)(x + (size_t)row * IN_F + k0 + 4);
    // fp8 quantize-write (8 bytes, x read exactly once grid-wide)
    int p0 = __builtin_amdgcn_cvt_pk_fp8_f32(xa.x, xa.y, 0, false);
    p0 = __builtin_amdgcn_cvt_pk_fp8_f32(xa.z, xa.w, p0, true);
    int p1 = __builtin_amdgcn_cvt_pk_fp8_f32(xc.x, xc.y, 0, false);
    p1 = __builtin_amdgcn_cvt_pk_fp8_f32(xc.z, xc.w, p1, true);
    *(uint2*)(xb + (size_t)row * IN_F + k0) = make_uint2((uint32_t)p0, (uint32_t)p1);
    // bf16 A fragment
    union { unsigned short s[8]; short8 v; } af;
    af.s[0] = f2bf(xa.x); af.s[1] = f2bf(xa.y); af.s[2] = f2bf(xa.z); af.s[3] = f2bf(xa.w);
    af.s[4] = f2bf(xc.x); af.s[5] = f2bf(xc.y); af.s[6] = f2bf(xc.z); af.s[7] = f2bf(xc.w);
    // bf16 B fragment = cp[j=l15][same k], zero for j>=9
    union { unsigned short s[8]; short8 v; } bf;
    #pragma unroll
    for (int q = 0; q < 8; ++q) bf.s[q] = 0;
    if (l15 < 9) {
      const float4 ca = *(const float4*)(cp + (size_t)l15 * IN_F + k0);
      const float4 cc = *(const float4*)(cp + (size_t)l15 * IN_F + k0 + 4);
      bf.s[0] = f2bf(ca.x); bf.s[1] = f2bf(ca.y); bf.s[2] = f2bf(ca.z); bf.s[3] = f2bf(ca.w);
      bf.s[4] = f2bf(cc.x); bf.s[5] = f2bf(cc.y); bf.s[6] = f2bf(cc.z); bf.s[7] = f2bf(cc.w);
    }
    acc = __builtin_amdgcn_mfma_f32_16x16x32_bf16(af.v, bf.v, acc, 0, 0, 0);
  }
  // reduce 4 wave-partials (C/D: row m = l4*4+r, col n = l15)
  #pragma unroll
  for (int r = 0; r < 4; ++r) red[wave][l4 * 4 + r][l15] = acc[r];
  __syncthreads();
  if (tid < 144) {
    const int rr = tid / 9, j = tid % 9;
    const float v = red[0][rr][j] + red[1][rr][j] + red[2][rr][j] + red[3][rr][j];
    ps[((size_t)h * NROWS + rg * 16 + rr) * 9 + j] = v;
  }
}

// ---- prepass 2: s = ps[0] + ps[1] ----
__global__ void s_reduce2(const float* __restrict__ ps, float* __restrict__ s) {
  const int row = blockIdx.x * 256 + threadIdx.x;
  #pragma unroll
  for (int j = 0; j < 9; ++j)
    s[row * 9 + j] = ps[(size_t)row * 9 + j] + ps[((size_t)NROWS + row) * 9 + j];
}

// ---- prepass 3: resid * 64 -> fp8 e4m3 ----
__global__ __launch_bounds__(256) void rq(const float* __restrict__ r,
                                          unsigned char* __restrict__ rb) {
  const int i = blockIdx.x * 256 + threadIdx.x;
  const float4* rv = (const float4*)r + (size_t)i * 4;
  uint32_t pk4[4];
  #pragma unroll
  for (int g = 0; g < 4; ++g) {
    float4 v = rv[g];
    int pk = __builtin_amdgcn_cvt_pk_fp8_f32(v.x * 64.f, v.y * 64.f, 0, false);
    pk = __builtin_amdgcn_cvt_pk_fp8_f32(v.z * 64.f, v.w * 64.f, pk, true);
    pk4[g] = (uint32_t)pk;
  }
  ((uint4*)rb)[i] = make_uint4(pk4[0], pk4[1], pk4[2], pk4[3]);
}

#define MFMA_FP8(d, av, bv) \
  d = __builtin_amdgcn_mfma_scale_f32_32x32x64_f8f6f4( \
      av, bv, d, 0, 0, 0, 0x7F7F7F7F, 0, 0x7F7F7F7F)

// ---- main GEMM (EXACT round-8 kernel, validated): y = (xb.rb^T)/64 + spline(s) + bias
// 128x128 tile, BK=64, 4 waves (2x2, 64x64), TRIPLE-buffered 48 KB LDS ->
// 3 blk/CU, distance-2 prefetch, counted vmcnt(4), single barrier/interval.
__global__ __launch_bounds__(256, 3) void gemm_fp8(
    const unsigned char* __restrict__ A,   // xb [8192][4096]
    const unsigned char* __restrict__ B,   // rb [4096][4096] (x64)
    const float* __restrict__ S,           // s [8192][9]
    const float* __restrict__ bias,
    float* __restrict__ C) {
  __shared__ unsigned char lds[3 * 16384];   // [buf][A|B][64 lines x 128 B]

  const int tid = threadIdx.x;
  const int lane = tid & 63;
  const int wave = tid >> 6;    // 0..3
  const int wr = wave >> 1;     // M half of tile
  const int wn = wave & 1;      // N half
  const int l31 = lane & 31;
  const int lh = lane >> 5;

  // XCD-aware swizzle (2048 % 8 == 0 -> bijective)
  const int bs = (blockIdx.x & 7) * 256 + (blockIdx.x >> 3);
  const int bm = bs >> 5;       // 64 M-tiles
  const int bn = bs & 31;       // 32 N-tiles
  const size_t row0 = (size_t)bm * 128;
  const size_t col0 = (size_t)bn * 128;

  auto stage = [&](int buf, int ab, int half, const unsigned char* __restrict__ src,
                   size_t grow0, int kt) {
    const int ls = (tid & 7) ^ ((tid >> 3) & 7);
    const int r = half * 64 + 2 * (tid >> 3) + (ls >> 2);
    const unsigned char* g = src + (grow0 + r) * (size_t)IN_F + kt * 64 + (ls & 3) * 16;
    unsigned char* d = lds + buf * 16384 + ab * 8192 + half * 4096 + (tid >> 6) * 1024;
    __builtin_amdgcn_global_load_lds(
        (const __attribute__((address_space(1))) void*)g,
        (__attribute__((address_space(3))) void*)d, 16, 0, 0);
  };
  auto stage_tile = [&](int buf, int kt) {
    stage(buf, 0, 0, A, row0, kt); stage(buf, 0, 1, A, row0, kt);
    stage(buf, 1, 0, B, col0, kt); stage(buf, 1, 1, B, col0, kt);
  };
  auto ldf = [&](int buf, int ab, int rbase, int s2) -> int4v {
    const int r = rbase + l31;
    const int sl = (r & 1) * 4 + lh * 2 + s2;
    const int L = r >> 1;
    return *(const int4v*)&lds[buf * 16384 + ab * 8192 + L * 128 + ((sl ^ (L & 7)) * 16)];
  };

  f32x16 acc[2][2] = {};

  stage_tile(0, 0);
  stage_tile(1, 1);
  asm volatile("s_waitcnt vmcnt(4)" ::: "memory");
  __builtin_amdgcn_s_barrier();

  int cur = 0, nx2 = 2;
  #pragma unroll 1
  for (int t = 0; t < NT; ++t) {
    const bool more = (t + 2 < NT);
    if (more) stage_tile(nx2, t + 2);

    union { int8v v8; int4v v4[2]; } a0, a1, b0, b1;
    a0.v4[0] = ldf(cur, 0, wr * 64 + 0,  0); a0.v4[1] = ldf(cur, 0, wr * 64 + 0,  1);
    a1.v4[0] = ldf(cur, 0, wr * 64 + 32, 0); a1.v4[1] = ldf(cur, 0, wr * 64 + 32, 1);
    b0.v4[0] = ldf(cur, 1, wn * 64 + 0,  0); b0.v4[1] = ldf(cur, 1, wn * 64 + 0,  1);
    b1.v4[0] = ldf(cur, 1, wn * 64 + 32, 0); b1.v4[1] = ldf(cur, 1, wn * 64 + 32, 1);
    __builtin_amdgcn_s_setprio(1);
    MFMA_FP8(acc[0][0], a0.v8, b0.v8);
    MFMA_FP8(acc[0][1], a0.v8, b1.v8);
    MFMA_FP8(acc[1][0], a1.v8, b0.v8);
    MFMA_FP8(acc[1][1], a1.v8, b1.v8);
    __builtin_amdgcn_s_setprio(0);

    asm volatile("s_waitcnt lgkmcnt(0)" ::: "memory");
    if (more) {
      asm volatile("s_waitcnt vmcnt(4)" ::: "memory");
    } else {
      asm volatile("s_waitcnt vmcnt(0)" ::: "memory");
    }
    __builtin_amdgcn_s_barrier();

    cur = (cur == 2) ? 0 : cur + 1;
    nx2 = (nx2 == 2) ? 0 : nx2 + 1;
  }

  // epilogue: y = acc/64 + Catmull-Rom(o) . s[n][j-1..j+2] + bias[o]
  // D layout (32x32): col = lane&31, row = (reg&3) + 8*(reg>>2) + 4*(lane>>5)
  const float inv64 = 0.015625f;
  #pragma unroll
  for (int ni = 0; ni < 2; ++ni) {
    const int o = (int)col0 + wn * 64 + ni * 32 + l31;
    float ts = ((float)o / 4095.0f) * 8.0f;
    int j = (int)floorf(ts);
    j = j < 1 ? 1 : (j > 6 ? 6 : j);
    float t = ts - (float)j;
    float t2 = t * t, t3 = t2 * t;
    const float c0 = -0.5f * t3 + t2 - 0.5f * t;
    const float c1 = 1.5f * t3 - 2.5f * t2 + 1.0f;
    const float c2 = -1.5f * t3 + 2.0f * t2 + 0.5f * t;
    const float c3 = 0.5f * t3 - 0.5f * t2;
    const float bv = bias[o];
    #pragma unroll
    for (int mi = 0; mi < 2; ++mi) {
      #pragma unroll
      for (int rg = 0; rg < 16; ++rg) {
        const int n = (int)row0 + wr * 64 + mi * 32 + (rg & 3) + 8 * (rg >> 2) + 4 * lh;
        const float* sr = S + n * 9 + (j - 1);
        C[(size_t)n * OUT_F + o] =
            acc[mi][ni][rg] * inv64 + c0 * sr[0] + c1 * sr[1] + c2 * sr[2] + c3 * sr[3] + bv;
      }
    }
  }
}

// ---- safety net: fp32 tiled GEMM w/ on-the-fly weight ----
static __device__ __forceinline__ void cr_coeffs(int o, int& j, float& c0, float& c1,
                                                 float& c2, float& c3) {
  float ts = ((float)o / 4095.0f) * 8.0f;
  j = (int)floorf(ts);
  j = j < 1 ? 1 : (j > 6 ? 6 : j);
  float t = ts - (float)j;
  float t2 = t * t, t3 = t2 * t;
  c0 = -0.5f * t3 + t2 - 0.5f * t;
  c1 = 1.5f * t3 - 2.5f * t2 + 1.0f;
  c2 = -1.5f * t3 + 2.0f * t2 + 0.5f * t;
  c3 = 0.5f * t3 - 0.5f * t2;
}

__global__ void fallback_gemm(const float* __restrict__ x, const float* __restrict__ cp,
                              const float* __restrict__ resid, const float* __restrict__ bias,
                              float* __restrict__ out) {
  __shared__ float xs[64][32];
  __shared__ float ws[64][33];
  const int tid = threadIdx.x;
  const int bm = blockIdx.x / (OUT_F / 64);
  const int bn = blockIdx.x % (OUT_F / 64);
  const int row0 = bm * 64, col0 = bn * 64;
  const int tr = tid >> 4, tc = tid & 15;
  float acc[4][4] = {};
  for (int k0 = 0; k0 < IN_F; k0 += 32) {
    #pragma unroll
    for (int q = 0; q < 8; ++q) {
      int e = q * 256 + tid;
      int r = e >> 5, cc = e & 31;
      xs[r][cc] = x[(size_t)(row0 + r) * IN_F + k0 + cc];
      int o = col0 + r;
      int j; float c0, c1, c2, c3;
      cr_coeffs(o, j, c0, c1, c2, c3);
      size_t ci = (size_t)(j - 1) * IN_F + k0 + cc;
      ws[r][cc] = c0 * cp[ci] + c1 * cp[ci + IN_F] + c2 * cp[ci + 2 * IN_F] +
                  c3 * cp[ci + 3 * IN_F] + resid[(size_t)o * IN_F + k0 + cc];
    }
    __syncthreads();
    #pragma unroll
    for (int kk = 0; kk < 32; ++kk) {
      float xv[4], wv[4];
      #pragma unroll
      for (int i = 0; i < 4; ++i) xv[i] = xs[tr * 4 + i][kk];
      #pragma unroll
      for (int i = 0; i < 4; ++i) wv[i] = ws[tc * 4 + i][kk];
      #pragma unroll
      for (int i = 0; i < 4; ++i)
        #pragma unroll
        for (int jj = 0; jj < 4; ++jj) acc[i][jj] += xv[i] * wv[jj];
    }
    __syncthreads();
  }
  #pragma unroll
  for (int i = 0; i < 4; ++i)
    #pragma unroll
    for (int jj = 0; jj < 4; ++jj) {
      int row = row0 + tr * 4 + i, col = col0 + tc * 4 + jj;
      out[(size_t)row * OUT_F + col] = acc[i][jj] + bias[col];
    }
}

extern "C" void kernel_launch(void* const* d_in, const int* in_sizes, int n_in,
                              void* d_out, int out_size, void* d_ws, size_t ws_size,
                              hipStream_t stream) {
  const float* x = (const float*)d_in[0];
  const float* cp = (const float*)d_in[1];
  const float* resid = (const float*)d_in[2];
  const float* bias = (const float*)d_in[3];
  float* out = (float*)d_out;

  const size_t xb_b = (size_t)NROWS * IN_F;        // 33,554,432
  const size_t rb_b = (size_t)OUT_F * IN_F;        // 16,777,216
  const size_t s_b = (size_t)NROWS * 9 * 4;        // 294,912
  const size_t ps_b = (size_t)2 * NROWS * 9 * 4;   // 589,824

  if (ws_size >= xb_b + rb_b + s_b + ps_b) {
    unsigned char* xb = (unsigned char*)d_ws;
    unsigned char* rb = xb + xb_b;
    float* s = (float*)(rb + rb_b);
    float* ps = (float*)((unsigned char*)s + s_b);
    hipLaunchKernelGGL(xqs_mfma, dim3(1024), dim3(256), 0, stream, x, cp, xb, ps);
    hipLaunchKernelGGL(s_reduce2, dim3(32), dim3(256), 0, stream, ps, s);
    hipLaunchKernelGGL(rq, dim3(4096), dim3(256), 0, stream, resid, rb);
    hipLaunchKernelGGL(gemm_fp8, dim3(2048), dim3(256), 0, stream, xb, rb, s, bias, out);
  } else {
    hipLaunchKernelGGL(fallback_gemm, dim3((NROWS / 64) * (OUT_F / 64)), dim3(256), 0,
                       stream, x, cp, resid, bias, out);
  }
}